// Round 16
// baseline (134.304 us; speedup 1.0000x reference)
//
#include <hip/hip_runtime.h>

using f16   = _Float16;
using f16x4 = __attribute__((ext_vector_type(4))) _Float16;
using f16x8 = __attribute__((ext_vector_type(8))) _Float16;
using f32x4 = __attribute__((ext_vector_type(4))) float;

#define BDIM 4
#define EDIM 512
#define LDIM 512
#define VDIM 32000
#define RDIM 2048            // B*L
#define INV_TAU 0.1f

using gcvoid = const __attribute__((address_space(1))) void;
using lvoid  = __attribute__((address_space(3))) void;

__device__ __forceinline__ void gload_lds16(const void* g, void* l) {
  __builtin_amdgcn_global_load_lds((gcvoid*)g, (lvoid*)l, 16, 0, 0);
}

// ---------------- kernel 1 (merged prep): one dispatch does
//   blocks [0,2048)    : M [V,E] f32 -> B16 f16 (stream convert, 16B stores)
//   blocks [2048,2080) : DE -> A16 transpose+convert + partial[r] = EN.DE (plain store)
//   block  2080        : zero down[2048]
#define CVTM_BLOCKS 2048
__global__ void prep_kernel(const float* __restrict__ M, const float* __restrict__ DE,
                            const float* __restrict__ EN, f16* __restrict__ B16,
                            f16* __restrict__ A16, float* __restrict__ partial,
                            float* __restrict__ down) {
  const int bid = blockIdx.x;
  const int t   = threadIdx.x;

  if (bid < CVTM_BLOCKS) {
    const size_t N8 = (size_t)VDIM * EDIM / 8;
    const size_t stride = (size_t)CVTM_BLOCKS * 256;
    for (size_t i = (size_t)bid * 256 + t; i < N8; i += stride) {
      float4 v0 = reinterpret_cast<const float4*>(M)[i * 2 + 0];
      float4 v1 = reinterpret_cast<const float4*>(M)[i * 2 + 1];
      f16x8 h = { (f16)v0.x, (f16)v0.y, (f16)v0.z, (f16)v0.w,
                  (f16)v1.x, (f16)v1.y, (f16)v1.z, (f16)v1.w };
      reinterpret_cast<f16x8*>(B16)[i] = h;
    }
    return;
  }

  if (bid == CVTM_BLOCKS + 32) {
#pragma unroll
    for (int j = 0; j < 8; ++j) down[t + j * 256] = 0.f;
    return;
  }

  // ---- cvtA + partial: one block per (b, l0) stripe, loops 8 e-tiles ----
  __shared__ float tile[64][65];
  __shared__ float4 psum[16][16];           // [e-group][l4-group]
  const int bid2 = bid - CVTM_BLOCKS;       // 0..31
  const int b  = bid2 >> 3;
  const int l0 = (bid2 & 7) * 64;
  float a0 = 0.f, a1 = 0.f, a2 = 0.f, a3 = 0.f;

  for (int e0 = 0; e0 < 512; e0 += 64) {
#pragma unroll
    for (int i = 0; i < 4; ++i) {
      int idx = t + i * 256;
      int el  = idx >> 4;
      int l4  = (idx & 15) * 4;
      size_t base = (size_t)(b * 512 + e0 + el) * 512 + l0 + l4;
      float4 v = *reinterpret_cast<const float4*>(DE + base);
      float4 u = *reinterpret_cast<const float4*>(EN + base);
      tile[el][l4 + 0] = v.x;
      tile[el][l4 + 1] = v.y;
      tile[el][l4 + 2] = v.z;
      tile[el][l4 + 3] = v.w;
      a0 += v.x * u.x; a1 += v.y * u.y; a2 += v.z * u.z; a3 += v.w * u.w;
    }
    __syncthreads();
#pragma unroll
    for (int i = 0; i < 4; ++i) {
      int idx = t + i * 256;
      int ll  = idx >> 4;
      int e4  = (idx & 15) * 4;
      f16x4 h;
      h[0] = (f16)tile[e4 + 0][ll];
      h[1] = (f16)tile[e4 + 1][ll];
      h[2] = (f16)tile[e4 + 2][ll];
      h[3] = (f16)tile[e4 + 3][ll];
      *reinterpret_cast<f16x4*>(A16 + (size_t)(b * 512 + l0 + ll) * 512 + e0 + e4) = h;
    }
    __syncthreads();
  }

  psum[t >> 4][t & 15] = make_float4(a0, a1, a2, a3);
  __syncthreads();
  if (t < 64) {
    const float* pcol = reinterpret_cast<const float*>(&psum[0][0]);
    float s = 0.f;
#pragma unroll
    for (int g = 0; g < 16; ++g) s += pcol[g * 64 + t];
    partial[(b << 9) + l0 + t] = s;
  }
}

// ---------------- kernel 2: BARRIER-FREE single-wave GEMM + exp + vocab-sum
// Block = 1 wave (64 thr), tile 64x128, grid 8000 = 32 rt x 250 ct.
// Private ring-3 LDS (3 x 12KB = 36KB -> 4 blocks/CU). Each wave stages ONLY
// the rows it reads (A 4 instrs + B 8 instrs per K-tile) -> per-wave counted
// vmcnt/lgkmcnt are exact, NO s_barrier in the whole kernel.
// Software pipeline per iter t: lgkmcnt(0) [frags t ready, issued iter t-1]
// -> vmcnt(12) [K(t+1) landed, staged 2 iters ago] -> ds_read frags t+1 ->
// stage K(t+3) into slot t%3 [freed by the lgkmcnt(0) above] -> 32 MFMA.
// Ledger: steady in-flight = K(t+2)+K(t+3) = 24; vmcnt(0) only at t=14.
// Swizzle involution (verified 0-conflict R3..R15): LDS granule g of row r
// holds global k-chunk g ^ ((r>>1)&3); reads use koff = (kc ^ ((lane>>1)&3))*16.
__global__ __launch_bounds__(64, 1) void gemm_kernel(const f16* __restrict__ A16,
                                                     const f16* __restrict__ B16,
                                                     float* __restrict__ down) {
  __shared__ __align__(16) char sm[3][12288];   // per buf: A[64][32] | B[128][32] f16
  const int orig = blockIdx.x;                  // 8000 = 8 * 1000 (bijective)
  const int wgid = (orig & 7) * 1000 + (orig >> 3);
  const int rt   = wgid & 31;                   // 32 row tiles of 64
  const int ct   = wgid >> 5;                   // 250 col tiles of 128
  const int r0   = rt * 64, c0 = ct * 128;
  const int lane = threadIdx.x;                 // single wave

  const int srow = lane >> 2;                   // staging row within 16-row group
  const int sel  = ((lane & 3) ^ ((lane >> 3) & 3)) * 8;   // inverse-swz src granule

  auto stage = [&](int buf, int t) {
    const int kbase = t * 32;
#pragma unroll
    for (int i = 0; i < 4; ++i)                 // A rows r0..r0+63
      gload_lds16(A16 + (size_t)(r0 + i * 16 + srow) * 512 + kbase + sel,
                  &sm[buf][i * 1024]);
#pragma unroll
    for (int i = 0; i < 8; ++i)                 // B rows c0..c0+127
      gload_lds16(B16 + (size_t)(c0 + i * 16 + srow) * 512 + kbase + sel,
                  &sm[buf][4096 + i * 1024]);
  };

  f32x4 acc[4][8] = {};
  const int koff  = ((lane >> 4) ^ ((lane >> 1) & 3)) * 16;
  const int abase = (lane & 15) * 64 + koff;    // + mi*1024
  const int bbase = 4096 + (lane & 15) * 64 + koff;  // + ni*1024

  f16x8 af[2][4], bf[2][8];

  // prologue: stage K0,K1; wait K0 (24 in flight -> 12); read K0 frags; stage K2
  stage(0, 0);
  stage(1, 1);
  asm volatile("s_waitcnt vmcnt(12)" ::: "memory");
#pragma unroll
  for (int mi = 0; mi < 4; ++mi)
    af[0][mi] = *reinterpret_cast<const f16x8*>(&sm[0][abase + mi * 1024]);
#pragma unroll
  for (int ni = 0; ni < 8; ++ni)
    bf[0][ni] = *reinterpret_cast<const f16x8*>(&sm[0][bbase + ni * 1024]);
  stage(2, 2);                                  // in flight: K1(12) + K2(12)

#pragma unroll
  for (int t = 0; t < 16; ++t) {
    const int s = t & 1, ns = s ^ 1;            // compile-time after unroll

    asm volatile("s_waitcnt lgkmcnt(0)" ::: "memory");   // frags t ready
    __builtin_amdgcn_sched_barrier(0);                    // rule 18

    if (t < 14)       asm volatile("s_waitcnt vmcnt(12)" ::: "memory"); // K(t+1) landed
    else if (t == 14) asm volatile("s_waitcnt vmcnt(0)"  ::: "memory"); // K15 landed

    if (t < 15) {                               // prefetch frags t+1 (hide under MFMA)
      const int nb = (t + 1) % 3;
#pragma unroll
      for (int mi = 0; mi < 4; ++mi)
        af[ns][mi] = *reinterpret_cast<const f16x8*>(&sm[nb][abase + mi * 1024]);
#pragma unroll
      for (int ni = 0; ni < 8; ++ni)
        bf[ns][ni] = *reinterpret_cast<const f16x8*>(&sm[nb][bbase + ni * 1024]);
    }
    if (t <= 12) stage(t % 3, t + 3);           // slot freed by lgkmcnt(0) above

    __builtin_amdgcn_s_setprio(1);
#pragma unroll
    for (int mi = 0; mi < 4; ++mi)
#pragma unroll
      for (int ni = 0; ni < 8; ++ni)
        acc[mi][ni] = __builtin_amdgcn_mfma_f32_16x16x32_f16(
            af[s][mi], bf[s][ni], acc[mi][ni], 0, 0, 0);
    __builtin_amdgcn_s_setprio(0);
  }

  // epilogue (no barrier needed: single wave): exp + 16-col shuffle reduce,
  // one atomicAdd per row. D layout: col = lane&15, row = (lane>>4)*4 + j.
#pragma unroll
  for (int mi = 0; mi < 4; ++mi) {
    float s0 = 0.f, s1 = 0.f, s2 = 0.f, s3 = 0.f;
#pragma unroll
    for (int ni = 0; ni < 8; ++ni) {
      f32x4 v = acc[mi][ni];
      s0 += __expf(INV_TAU * v[0]);
      s1 += __expf(INV_TAU * v[1]);
      s2 += __expf(INV_TAU * v[2]);
      s3 += __expf(INV_TAU * v[3]);
    }
#pragma unroll
    for (int m = 1; m <= 8; m <<= 1) {
      s0 += __shfl_xor(s0, m);
      s1 += __shfl_xor(s1, m);
      s2 += __shfl_xor(s2, m);
      s3 += __shfl_xor(s3, m);
    }
    if ((lane & 15) == 0) {
      int row = r0 + mi * 16 + (lane >> 4) * 4;
      atomicAdd(&down[row + 0], s0);
      atomicAdd(&down[row + 1], s1);
      atomicAdd(&down[row + 2], s2);
      atomicAdd(&down[row + 3], s3);
    }
  }
}

// ---------------- kernel 3: out[0] = sum_r exp(partial[r]/tau) / down[r]
// single block, plain store (no atomic, no pre-zero of d_out needed)
__global__ void finalize2_kernel(const float* __restrict__ partial,
                                 const float* __restrict__ down,
                                 float* __restrict__ out) {
  __shared__ float red[4];
  const int t = threadIdx.x;
  const int lane = t & 63;
  const int w = t >> 6;
  float val = 0.f;
#pragma unroll
  for (int j = 0; j < 8; ++j) {
    int r = t + j * 256;
    val += __expf(INV_TAU * partial[r]) / down[r];
  }
#pragma unroll
  for (int m = 1; m <= 32; m <<= 1) val += __shfl_xor(val, m);
  if (lane == 0) red[w] = val;
  __syncthreads();
  if (t == 0) out[0] = red[0] + red[1] + red[2] + red[3];
}

extern "C" void kernel_launch(void* const* d_in, const int* in_sizes, int n_in,
                              void* d_out, int out_size, void* d_ws, size_t ws_size,
                              hipStream_t stream) {
  const float* EN = (const float*)d_in[0];
  const float* DE = (const float*)d_in[1];
  const float* M  = (const float*)d_in[2];

  // ws layout: down[2048] f32 | partial[2048] f32 | A16 [2048*512] f16 | B16 [32000*512] f16
  float* down    = (float*)d_ws;
  float* partial = (float*)((char*)d_ws + 8192);
  f16* A16 = (f16*)((char*)d_ws + 16384);
  f16* B16 = (f16*)((char*)d_ws + 16384 + (size_t)RDIM * EDIM * 2);
  const size_t need = 16384 + (size_t)RDIM * EDIM * 2 + (size_t)VDIM * EDIM * 2;

  if (ws_size < need) {                      // diagnosable fail: out = 0
    hipMemsetAsync(d_out, 0, sizeof(float), stream);
    return;
  }

  prep_kernel<<<CVTM_BLOCKS + 33, 256, 0, stream>>>(M, DE, EN, B16, A16, partial, down);
  gemm_kernel<<<8000, 64, 0, stream>>>(A16, B16, down);
  finalize2_kernel<<<1, 256, 0, stream>>>(partial, down, (float*)d_out);
}

// Round 17
// 105.994 us; speedup vs baseline: 1.2671x; 1.2671x over previous
//
#include <hip/hip_runtime.h>

using f16   = _Float16;
using f16x4 = __attribute__((ext_vector_type(4))) _Float16;
using f16x8 = __attribute__((ext_vector_type(8))) _Float16;
using f32x4 = __attribute__((ext_vector_type(4))) float;

#define BDIM 4
#define EDIM 512
#define LDIM 512
#define VDIM 32000
#define RDIM 2048            // B*L
#define INV_TAU 0.1f

using gcvoid = const __attribute__((address_space(1))) void;
using lvoid  = __attribute__((address_space(3))) void;

__device__ __forceinline__ void gload_lds16(const void* g, void* l) {
  __builtin_amdgcn_global_load_lds((gcvoid*)g, (lvoid*)l, 16, 0, 0);
}

// ---------------- kernel 1 (merged prep): one dispatch does
//   blocks [0,32)      : DE -> A16 transpose+convert + partial[r] = EN.DE (plain store)
//   block  32          : zero down[2048]
//   blocks [33,2081)   : M [V,E] f32 -> B16 f16 (stream convert, 16B stores)
// cvtA blocks FIRST so their ~4us hides under the BW-bound cvtM stream.
#define CVTM_BLOCKS 2048
#define PREP_HEAD   33
__global__ void prep_kernel(const float* __restrict__ M, const float* __restrict__ DE,
                            const float* __restrict__ EN, f16* __restrict__ B16,
                            f16* __restrict__ A16, float* __restrict__ partial,
                            float* __restrict__ down) {
  const int bid = blockIdx.x;
  const int t   = threadIdx.x;

  if (bid >= PREP_HEAD) {
    // ---- cvtM part ----
    const size_t N8 = (size_t)VDIM * EDIM / 8;
    const size_t stride = (size_t)CVTM_BLOCKS * 256;
    for (size_t i = (size_t)(bid - PREP_HEAD) * 256 + t; i < N8; i += stride) {
      float4 v0 = reinterpret_cast<const float4*>(M)[i * 2 + 0];
      float4 v1 = reinterpret_cast<const float4*>(M)[i * 2 + 1];
      f16x8 h = { (f16)v0.x, (f16)v0.y, (f16)v0.z, (f16)v0.w,
                  (f16)v1.x, (f16)v1.y, (f16)v1.z, (f16)v1.w };
      reinterpret_cast<f16x8*>(B16)[i] = h;
    }
    return;
  }

  if (bid == 32) {
    // ---- down-zero part ----
#pragma unroll
    for (int j = 0; j < 8; ++j) down[t + j * 256] = 0.f;
    return;
  }

  // ---- cvtA + partial: one block per (b, l0) stripe, loops 8 e-tiles ----
  __shared__ float tile[64][65];
  __shared__ float4 psum[16][16];           // [e-group][l4-group]
  const int b  = bid >> 3;
  const int l0 = (bid & 7) * 64;
  float a0 = 0.f, a1 = 0.f, a2 = 0.f, a3 = 0.f;

  for (int e0 = 0; e0 < 512; e0 += 64) {
#pragma unroll
    for (int i = 0; i < 4; ++i) {
      int idx = t + i * 256;
      int el  = idx >> 4;
      int l4  = (idx & 15) * 4;
      size_t base = (size_t)(b * 512 + e0 + el) * 512 + l0 + l4;
      float4 v = *reinterpret_cast<const float4*>(DE + base);
      float4 u = *reinterpret_cast<const float4*>(EN + base);
      tile[el][l4 + 0] = v.x;
      tile[el][l4 + 1] = v.y;
      tile[el][l4 + 2] = v.z;
      tile[el][l4 + 3] = v.w;
      a0 += v.x * u.x; a1 += v.y * u.y; a2 += v.z * u.z; a3 += v.w * u.w;
    }
    __syncthreads();
#pragma unroll
    for (int i = 0; i < 4; ++i) {
      int idx = t + i * 256;
      int ll  = idx >> 4;
      int e4  = (idx & 15) * 4;
      f16x4 h;
      h[0] = (f16)tile[e4 + 0][ll];
      h[1] = (f16)tile[e4 + 1][ll];
      h[2] = (f16)tile[e4 + 2][ll];
      h[3] = (f16)tile[e4 + 3][ll];
      *reinterpret_cast<f16x4*>(A16 + (size_t)(b * 512 + l0 + ll) * 512 + e0 + e4) = h;
    }
    __syncthreads();
  }

  psum[t >> 4][t & 15] = make_float4(a0, a1, a2, a3);
  __syncthreads();
  if (t < 64) {
    const float* pcol = reinterpret_cast<const float*>(&psum[0][0]);
    float s = 0.f;
#pragma unroll
    for (int g = 0; g < 16; ++g) s += pcol[g * 64 + t];
    partial[(b << 9) + l0 + t] = s;
  }
}

// ---------------- kernel 2: fused GEMM + exp + vocab-sum  (R12/R15, byte-identical)
// 128x128 tile, BK=32, 16 K-tiles, ring-3 LDS (48KB, 3 blk/CU), counted vmcnt
// (stage K(t+2) during t; boundary vmcnt(4) lgkmcnt(0), vmcnt(0) at t=14).
// Granule swizzle both sides (verified involution): LDS granule g of row r
// holds global k-chunk g ^ ((r>>1)&3). 0 bank conflicts (R3..R15).
// Epilogue: cross-wc LDS pair-reduce -> ONE atomic per down[] row per block.
__global__ __launch_bounds__(256, 3) void gemm_kernel(const f16* __restrict__ A16,
                                                      const f16* __restrict__ B16,
                                                      float* __restrict__ down) {
  __shared__ __align__(16) char sm[3][16384];   // per buf: A[128][32] | B[128][32] f16
  const int orig = blockIdx.x;                  // 4000 blocks = 8 * 500 (bijective)
  const int bid  = (orig & 7) * 500 + (orig >> 3);
  const int rt   = bid & 15;                    // 16 row tiles
  const int ct   = bid >> 4;                    // 250 col tiles
  const int r0   = rt * 128, c0 = ct * 128;
  const int tid  = threadIdx.x;
  const int lane = tid & 63;
  const int w    = tid >> 6;
  const int wr   = w >> 1, wc = w & 1;

  const int srow = lane >> 2;
  const int sel  = ((lane & 3) ^ ((lane >> 3) & 3)) * 8;   // f16 elems

  auto stage = [&](int buf, int t) {
    const int kbase = t * 32;
#pragma unroll
    for (int i = 0; i < 2; ++i) {
      int instr = w * 2 + i;                    // 8 instrs cover 128 rows
      gload_lds16(A16 + (size_t)(r0 + instr * 16 + srow) * 512 + kbase + sel,
                  &sm[buf][instr * 1024]);
    }
#pragma unroll
    for (int i = 0; i < 2; ++i) {
      int instr = w * 2 + i;
      gload_lds16(B16 + (size_t)(c0 + instr * 16 + srow) * 512 + kbase + sel,
                  &sm[buf][8192 + instr * 1024]);
    }
  };

  f32x4 acc[4][4] = {};

  stage(0, 0);
  stage(1, 1);
  asm volatile("s_waitcnt vmcnt(4)" ::: "memory");
  __builtin_amdgcn_s_barrier();
  asm volatile("" ::: "memory");

  const int koff = (((lane >> 4) ^ ((lane >> 1) & 3)) * 16);
  const int arow = (wr * 64 + (lane & 15)) * 64;
  const int brow = (wc * 64 + (lane & 15)) * 64;

#pragma unroll
  for (int t = 0; t < 16; ++t) {
    const int cur = t % 3;
    f16x8 af[4], bf[4];
#pragma unroll
    for (int mi = 0; mi < 4; ++mi)
      af[mi] = *reinterpret_cast<const f16x8*>(&sm[cur][arow + mi * 1024 + koff]);
#pragma unroll
    for (int ni = 0; ni < 4; ++ni)
      bf[ni] = *reinterpret_cast<const f16x8*>(&sm[cur][8192 + brow + ni * 1024 + koff]);

    if (t + 2 < 16) stage((t + 2) % 3, t + 2);

    __builtin_amdgcn_s_setprio(1);
#pragma unroll
    for (int mi = 0; mi < 4; ++mi)
#pragma unroll
      for (int ni = 0; ni < 4; ++ni)
        acc[mi][ni] = __builtin_amdgcn_mfma_f32_16x16x32_f16(
            af[mi], bf[ni], acc[mi][ni], 0, 0, 0);
    __builtin_amdgcn_s_setprio(0);

    if (t < 15) {
      if (t <= 13) asm volatile("s_waitcnt vmcnt(4) lgkmcnt(0)" ::: "memory");
      else         asm volatile("s_waitcnt vmcnt(0) lgkmcnt(0)" ::: "memory");
      __builtin_amdgcn_s_barrier();
      asm volatile("" ::: "memory");
    }
  }

  // ---- epilogue: exp + 16-col shuffle reduce; cross-wc LDS pair-reduce;
  // one atomicAdd per row. D layout: col = lane&15, row = (lane>>4)*4 + j.
  __syncthreads();                              // all K-loop LDS reads complete
  float4* red = reinterpret_cast<float4*>(&sm[2][0]);   // 32 slots used
  float4 mysum[4];
#pragma unroll
  for (int mi = 0; mi < 4; ++mi) {
    float s0 = 0.f, s1 = 0.f, s2 = 0.f, s3 = 0.f;
#pragma unroll
    for (int ni = 0; ni < 4; ++ni) {
      f32x4 v = acc[mi][ni];
      s0 += __expf(INV_TAU * v[0]);
      s1 += __expf(INV_TAU * v[1]);
      s2 += __expf(INV_TAU * v[2]);
      s3 += __expf(INV_TAU * v[3]);
    }
#pragma unroll
    for (int m = 1; m <= 8; m <<= 1) {
      s0 += __shfl_xor(s0, m);
      s1 += __shfl_xor(s1, m);
      s2 += __shfl_xor(s2, m);
      s3 += __shfl_xor(s3, m);
    }
    mysum[mi] = make_float4(s0, s1, s2, s3);
    if (wc == 1 && (lane & 15) == 0)
      red[(wr * 4 + mi) * 4 + (lane >> 4)] = mysum[mi];
  }
  __syncthreads();
  if (wc == 0 && (lane & 15) == 0) {
    const int rbase = r0 + wr * 64;
#pragma unroll
    for (int mi = 0; mi < 4; ++mi) {
      float4 o = red[(wr * 4 + mi) * 4 + (lane >> 4)];
      int row = rbase + mi * 16 + (lane >> 4) * 4;
      atomicAdd(&down[row + 0], mysum[mi].x + o.x);
      atomicAdd(&down[row + 1], mysum[mi].y + o.y);
      atomicAdd(&down[row + 2], mysum[mi].z + o.z);
      atomicAdd(&down[row + 3], mysum[mi].w + o.w);
    }
  }
}

// ---------------- kernel 3: out[0] = sum_r exp(partial[r]/tau) / down[r]
// single block, plain store (no atomic, no pre-zero of d_out needed)
__global__ void finalize2_kernel(const float* __restrict__ partial,
                                 const float* __restrict__ down,
                                 float* __restrict__ out) {
  __shared__ float red[4];
  const int t = threadIdx.x;
  const int lane = t & 63;
  const int w = t >> 6;
  float val = 0.f;
#pragma unroll
  for (int j = 0; j < 8; ++j) {
    int r = t + j * 256;
    val += __expf(INV_TAU * partial[r]) / down[r];
  }
#pragma unroll
  for (int m = 1; m <= 32; m <<= 1) val += __shfl_xor(val, m);
  if (lane == 0) red[w] = val;
  __syncthreads();
  if (t == 0) out[0] = red[0] + red[1] + red[2] + red[3];
}

extern "C" void kernel_launch(void* const* d_in, const int* in_sizes, int n_in,
                              void* d_out, int out_size, void* d_ws, size_t ws_size,
                              hipStream_t stream) {
  const float* EN = (const float*)d_in[0];
  const float* DE = (const float*)d_in[1];
  const float* M  = (const float*)d_in[2];

  // ws layout: down[2048] f32 | partial[2048] f32 | A16 [2048*512] f16 | B16 [32000*512] f16
  float* down    = (float*)d_ws;
  float* partial = (float*)((char*)d_ws + 8192);
  f16* A16 = (f16*)((char*)d_ws + 16384);
  f16* B16 = (f16*)((char*)d_ws + 16384 + (size_t)RDIM * EDIM * 2);
  const size_t need = 16384 + (size_t)RDIM * EDIM * 2 + (size_t)VDIM * EDIM * 2;

  if (ws_size < need) {                      // diagnosable fail: out = 0
    hipMemsetAsync(d_out, 0, sizeof(float), stream);
    return;
  }

  prep_kernel<<<CVTM_BLOCKS + PREP_HEAD, 256, 0, stream>>>(M, DE, EN, B16, A16, partial, down);
  gemm_kernel<<<4000, 256, 0, stream>>>(A16, B16, down);
  finalize2_kernel<<<1, 256, 0, stream>>>(partial, down, (float*)d_out);
}